// Round 2
// baseline (33724.493 us; speedup 1.0000x reference)
//
#include <hip/hip_runtime.h>
#include <math.h>

// Problem constants
#define BB 16
#define TT 128
#define F_IN 240
#define E_DIM 1024
#define HH 320
#define G4 1280        // 4*H
#define JHD 512
#define VV 29
#define BLANKV 28
#define MAXSYM 3
#define LBUF (TT*MAXSYM) // 384

#define NB 40          // persistent grid blocks
#define DBLK 39        // block that runs phase D

// Workspace layout (float offsets)
#define OFF_FPROJ 0ul                        // 2048*512
#define OFF_W0T   1048576ul                  // 320*1280 blocked [80][1280][4]
#define OFF_W1AT  (OFF_W0T + 409600ul)
#define OFF_W1BT  (OFF_W1AT + 409600ul)
#define OFF_WJHT  (OFF_W1BT + 409600ul)      // [80][512][4]
#define OFF_EP    (OFF_WJHT + 163840ul)      // 29*1280
#define OFF_B1    (OFF_EP + 37120ul)         // 1280
#define OFF_WJ2T  (OFF_B1 + 1280ul)          // 29*512
#define OFF_H0    (OFF_WJ2T + 14848ul)       // 2*16*320
#define OFF_C0    (OFF_H0 + 10240ul)
#define OFF_H1    (OFF_C0 + 10240ul)
#define OFF_C1    (OFF_H1 + 10240ul)
#define OFF_HP    (OFF_C1 + 10240ul)         // 16*512
#define OFF_FLAGS (OFF_HP + 8192ul)          // ints: cur[16], last[16]
#define OFF_BAR   (OFF_FLAGS + 32ul)

#define SBUF 5120      // per-state-buffer stride (16*320)

__device__ __forceinline__ float sigmoidf(float x) {
    return 1.0f / (1.0f + expf(-x));
}

// ---- Prep: transposed/blocked weights + combined bias + Wj2^T ----
__global__ void prep_t_kernel(const float* __restrict__ Whh0,
                              const float* __restrict__ Wih1,
                              const float* __restrict__ Whh1,
                              const float* __restrict__ Wj1,
                              const float* __restrict__ bih1,
                              const float* __restrict__ bhh1,
                              const float* __restrict__ Wj2,
                              float* __restrict__ W0T, float* __restrict__ W1aT,
                              float* __restrict__ W1bT, float* __restrict__ WjhT,
                              float* __restrict__ b1, float* __restrict__ Wj2T) {
    int idx = blockIdx.x * 256 + threadIdx.x;
    if (idx < 409600) {
        int j = idx / 320, k = idx % 320;
        int d = (k >> 2) * (G4 * 4) + j * 4 + (k & 3);
        W0T[d]  = Whh0[idx];
        W1aT[d] = Wih1[idx];
        W1bT[d] = Whh1[idx];
        return;
    }
    int idx2 = idx - 409600;
    if (idx2 < 163840) {
        int k = idx2 / 512, j = idx2 % 512;
        WjhT[(k >> 2) * (JHD * 4) + j * 4 + (k & 3)] = Wj1[(size_t)(1024 + k) * JHD + j];
        return;
    }
    int idx3 = idx2 - 163840;
    if (idx3 < G4) { b1[idx3] = bih1[idx3] + bhh1[idx3]; return; }
    int e = idx3 - G4;
    if (e < VV * JHD) {
        int v = e >> 9, k = e & 511;
        Wj2T[e] = Wj2[(size_t)k * VV + v];
    }
}

// ---- Prep: EP[v][j] = embed[v] @ Wih0[j,:] + bih0[j] + bhh0[j]; row 28 = bias only
__global__ void ep_kernel(const float* __restrict__ embed,
                          const float* __restrict__ Wih0,
                          const float* __restrict__ bih0,
                          const float* __restrict__ bhh0,
                          float* __restrict__ EP) {
    __shared__ __align__(16) float es[HH];
    int v = blockIdx.x;
    for (int k = threadIdx.x; k < HH; k += 256)
        es[k] = (v < VV - 1) ? embed[v * HH + k] : 0.0f;
    __syncthreads();
    for (int j = threadIdx.x; j < G4; j += 256) {
        float acc = bih0[j] + bhh0[j];
        if (v < VV - 1) {
            const float4* wr = (const float4*)(Wih0 + (size_t)j * HH);
            const float4* ev = (const float4*)es;
            #pragma unroll 4
            for (int k4 = 0; k4 < HH / 4; ++k4) {
                float4 w = wr[k4], e = ev[k4];
                acc += w.x * e.x + w.y * e.y + w.z * e.z + w.w * e.w;
            }
        }
        EP[v * G4 + j] = acc;
    }
}

// ---- Encoder + F_proj fused ----
__global__ __launch_bounds__(512) void enc_fproj_kernel(
    const float* __restrict__ x, const float* __restrict__ Wenc,
    const float* __restrict__ benc, const float* __restrict__ Wj1,
    const float* __restrict__ bj1,
    float* __restrict__ logits_out, float* __restrict__ Fproj) {
    __shared__ float xs[8][F_IN];
    __shared__ float ls[8][E_DIM];
    int row0 = blockIdx.x * 8;
    int tid = threadIdx.x;
    for (int i = tid; i < 8 * F_IN; i += 512)
        xs[i / F_IN][i % F_IN] = x[(size_t)row0 * F_IN + i];
    __syncthreads();
    for (int j = tid; j < E_DIM; j += 512) {
        float acc[8];
        float bv = benc[j];
        #pragma unroll
        for (int r = 0; r < 8; ++r) acc[r] = bv;
        for (int k = 0; k < F_IN; ++k) {
            float w = Wenc[(size_t)k * E_DIM + j];
            #pragma unroll
            for (int r = 0; r < 8; ++r) acc[r] += xs[r][k] * w;
        }
        #pragma unroll
        for (int r = 0; r < 8; ++r) {
            ls[r][j] = acc[r];
            logits_out[(size_t)(row0 + r) * E_DIM + j] = acc[r];
        }
    }
    __syncthreads();
    {
        int j = tid;
        float acc[8];
        float bv = bj1[j];
        #pragma unroll
        for (int r = 0; r < 8; ++r) acc[r] = bv;
        for (int k = 0; k < E_DIM; ++k) {
            float w = Wj1[(size_t)k * JHD + j];
            #pragma unroll
            for (int r = 0; r < 8; ++r) acc[r] += ls[r][k] * w;
        }
        #pragma unroll
        for (int r = 0; r < 8; ++r) Fproj[(size_t)(row0 + r) * JHD + j] = acc[r];
    }
}

// ---- Init: zero state, flags, barrier; fill labels with -1; out_lens passthrough
__global__ void init_kernel(const int* __restrict__ lens, float* ws,
                            float* __restrict__ out_lens_out,
                            float* __restrict__ labels_out) {
    int tid = threadIdx.x;
    float* st = ws + OFF_H0;
    for (int i = tid; i < 4 * 10240; i += 1024) st[i] = 0.0f;
    int* flags = (int*)(ws + OFF_FLAGS);
    if (tid < 16) flags[tid] = 0;             // cur
    else if (tid < 32) flags[tid] = BLANKV;   // last = 28 -> EP row 28 (SOS)
    if (tid == 32) *(unsigned*)(ws + OFF_BAR) = 0u;
    for (int i = tid; i < BB * LBUF; i += 1024) labels_out[i] = -1.0f;
    if (tid < BB) out_lens_out[tid] = (float)lens[tid];
}

__device__ __forceinline__ void gsync(unsigned* bar, unsigned target) {
    __syncthreads();
    if (threadIdx.x == 0) {
        __threadfence();            // release: write back this XCD's dirty L2
        atomicAdd(bar, 1u);
        while (__hip_atomic_load(bar, __ATOMIC_RELAXED, __HIP_MEMORY_SCOPE_AGENT) < target) {
            __builtin_amdgcn_s_sleep(1);
        }
        __threadfence();            // acquire: invalidate L1 + L2
    }
    __syncthreads();
}

// ---- Persistent lockstep decoder: 40 blocks x 1024 threads ----
__global__ __launch_bounds__(1024) void decode_persistent(
    const int* __restrict__ lens,
    const float* __restrict__ Fproj,
    const float* __restrict__ W0T, const float* __restrict__ W1aT,
    const float* __restrict__ W1bT, const float* __restrict__ WjhT,
    const float* __restrict__ Wj2T,
    const float* __restrict__ EP, const float* __restrict__ b1,
    const float* __restrict__ bj2,
    float* H0, float* C0, float* H1, float* C1, float* HP,
    int* flags, unsigned* bar,
    float* __restrict__ labels_out, float* __restrict__ counts_out) {

    const int tid = threadIdx.x;
    const int blk = blockIdx.x;
    volatile int* vcur  = flags;        // cur[16]
    volatile int* vlast = flags + 16;   // last[16]

    __shared__ float shbuf[JHD * 17 + VV * 16];   // jh (stride 17) + logits
    __shared__ int sMaxL;

    if (tid == 0) {
        int m = 0;
        for (int i = 0; i < BB; ++i) m = max(m, lens[i]);
        sMaxL = m;
    }
    __syncthreads();
    const int maxL = sMaxL;

    // per-item decode state lives in registers of block DBLK, threads 0..15
    int cnt = 0, cont = 0, myL = 0;
    if (blk == DBLK && tid < 16) myL = lens[tid];

    unsigned nsync = 0;
    int t = 0, s = 0;

    // common lane decomposition for phases A/B
    const int b    = tid & 15;
    const int half = (tid >> 4) & 1;
    const int g    = (tid >> 5) & 3;
    const int il   = tid >> 7;          // 0..7
    const int iAB  = blk * 8 + il;      // 0..319
    const int jAB  = g * HH + iAB;      // gate index 0..1279

    for (int sigma = 0; sigma < 3 * maxL; ++sigma) {
        const int curb = vcur[b];
        const int pend = curb ^ 1;

        // ================= Phase A: LSTM cell 0 =================
        {
            const float4* hv = (const float4*)(H0 + curb * SBUF + b * HH) + half * 40;
            const float*  wb = W0T + (size_t)(half * 40) * (G4 * 4) + jAB * 4;
            float acc = 0.f;
            #pragma unroll 8
            for (int kb = 0; kb < 40; ++kb) {
                float4 h = hv[kb];
                float4 w = *(const float4*)(wb + (size_t)kb * (G4 * 4));
                acc += h.x * w.x + h.y * w.y + h.z * w.z + h.w * w.w;
            }
            acc += __shfl_xor(acc, 16);
            if (!half) {
                acc += EP[(size_t)vlast[b] * G4 + jAB];
                shbuf[(il * 4 + g) * 16 + b] = acc;
            }
        }
        __syncthreads();
        if (tid < 128) {
            int bb = tid & 15, ii = (tid >> 4);
            int i = blk * 8 + ii;
            float gi = shbuf[(ii * 4 + 0) * 16 + bb];
            float gf = shbuf[(ii * 4 + 1) * 16 + bb];
            float gg = shbuf[(ii * 4 + 2) * 16 + bb];
            float go = shbuf[(ii * 4 + 3) * 16 + bb];
            int cb = vcur[bb], pd = cb ^ 1;
            float c = sigmoidf(gf) * C0[cb * SBUF + bb * HH + i] + sigmoidf(gi) * tanhf(gg);
            C0[pd * SBUF + bb * HH + i] = c;
            H0[pd * SBUF + bb * HH + i] = sigmoidf(go) * tanhf(c);
        }
        gsync(bar, ++nsync * NB);

        // ================= Phase B: LSTM cell 1 =================
        {
            const float4* hv = (const float4*)((half ? (H1 + curb * SBUF) : (H0 + pend * SBUF)) + b * HH);
            const float*  wb = (half ? W1bT : W1aT) + jAB * 4;
            float acc = 0.f;
            #pragma unroll 8
            for (int kb = 0; kb < 80; ++kb) {
                float4 h = hv[kb];
                float4 w = *(const float4*)(wb + (size_t)kb * (G4 * 4));
                acc += h.x * w.x + h.y * w.y + h.z * w.z + h.w * w.w;
            }
            acc += __shfl_xor(acc, 16);
            if (!half) {
                acc += b1[jAB];
                shbuf[(il * 4 + g) * 16 + b] = acc;
            }
        }
        __syncthreads();
        if (tid < 128) {
            int bb = tid & 15, ii = (tid >> 4);
            int i = blk * 8 + ii;
            float gi = shbuf[(ii * 4 + 0) * 16 + bb];
            float gf = shbuf[(ii * 4 + 1) * 16 + bb];
            float gg = shbuf[(ii * 4 + 2) * 16 + bb];
            float go = shbuf[(ii * 4 + 3) * 16 + bb];
            int cb = vcur[bb], pd = cb ^ 1;
            float c = sigmoidf(gf) * C1[cb * SBUF + bb * HH + i] + sigmoidf(gi) * tanhf(gg);
            C1[pd * SBUF + bb * HH + i] = c;
            H1[pd * SBUF + bb * HH + i] = sigmoidf(go) * tanhf(c);
        }
        gsync(bar, ++nsync * NB);

        // ================= Phase C: HP = h1_pending @ WjhT =================
        if (blk < 32) {
            int q = (tid >> 4) & 3;
            int jl = tid >> 6;              // 0..15
            int j = blk * 16 + jl;          // 0..511
            const float4* hv = (const float4*)(H1 + pend * SBUF + b * HH) + q * 20;
            const float*  wb = WjhT + (size_t)(q * 20) * (JHD * 4) + j * 4;
            float acc = 0.f;
            #pragma unroll 4
            for (int kb = 0; kb < 20; ++kb) {
                float4 h = hv[kb];
                float4 w = *(const float4*)(wb + (size_t)kb * (JHD * 4));
                acc += h.x * w.x + h.y * w.y + h.z * w.z + h.w * w.w;
            }
            acc += __shfl_xor(acc, 16);
            acc += __shfl_xor(acc, 32);
            if (q == 0) HP[b * JHD + j] = acc;
        }
        gsync(bar, ++nsync * NB);

        // ================= Phase D: joint + argmax + commit =================
        if (blk == DBLK) {
            {   // jh = relu(Fproj[b,t] + HP[b]) into LDS, stride 17 (conflict-free)
                int bb = tid >> 6, kl = tid & 63;
                const float* fp = Fproj + ((size_t)(bb * TT + t)) * JHD;
                const float* hp = HP + bb * JHD;
                #pragma unroll
                for (int u = 0; u < 8; ++u) {
                    int k = kl + 64 * u;
                    shbuf[k * 17 + bb] = fmaxf(fp[k] + hp[k], 0.f);
                }
            }
            __syncthreads();
            float* logitL = shbuf + JHD * 17;
            {
                int b2 = tid & 15, h2 = (tid >> 4) & 1, v = tid >> 5;
                if (v < VV) {
                    const float* w = Wj2T + v * JHD + h2 * 256;
                    const float* jcol = shbuf + (h2 * 256) * 17 + b2;
                    float acc = 0.f;
                    #pragma unroll 4
                    for (int k4 = 0; k4 < 64; ++k4) {
                        float4 wv = *(const float4*)(w + k4 * 4);
                        acc += wv.x * jcol[(k4 * 4 + 0) * 17]
                             + wv.y * jcol[(k4 * 4 + 1) * 17]
                             + wv.z * jcol[(k4 * 4 + 2) * 17]
                             + wv.w * jcol[(k4 * 4 + 3) * 17];
                    }
                    acc += __shfl_xor(acc, 16);
                    if (!h2) logitL[v * 16 + b2] = acc + bj2[v];
                }
            }
            __syncthreads();
            if (tid < 16) {
                float best = logitL[tid];
                int bk = 0;
                #pragma unroll
                for (int v2 = 1; v2 < VV; ++v2) {
                    float xx = logitL[v2 * 16 + tid];
                    if (xx > best) { best = xx; bk = v2; }
                }
                bool active = (t < myL) && (s == 0 || cont);
                bool emit = active && (bk != BLANKV);
                if (emit) {
                    labels_out[(size_t)tid * LBUF + cnt] = (float)bk;
                    cnt++;
                    vcur[tid] = vcur[tid] ^ 1;   // commit pending -> current
                    vlast[tid] = bk;
                }
                cont = emit ? 1 : 0;
            }
        }
        gsync(bar, ++nsync * NB);

        if (++s == MAXSYM) { s = 0; ++t; }
    }

    if (blk == DBLK && tid < 16) counts_out[tid] = (float)cnt;
}

extern "C" void kernel_launch(void* const* d_in, const int* in_sizes, int n_in,
                              void* d_out, int out_size, void* d_ws, size_t ws_size,
                              hipStream_t stream) {
    const float* x      = (const float*)d_in[0];
    const int*   lens   = (const int*)d_in[1];
    const float* Wenc   = (const float*)d_in[2];
    const float* benc   = (const float*)d_in[3];
    const float* embed  = (const float*)d_in[4];
    const float* Wih0   = (const float*)d_in[5];
    const float* Whh0   = (const float*)d_in[6];
    const float* bih0   = (const float*)d_in[7];
    const float* bhh0   = (const float*)d_in[8];
    const float* Wih1   = (const float*)d_in[9];
    const float* Whh1   = (const float*)d_in[10];
    const float* bih1   = (const float*)d_in[11];
    const float* bhh1   = (const float*)d_in[12];
    const float* Wj1    = (const float*)d_in[13];
    const float* bj1    = (const float*)d_in[14];
    const float* Wj2    = (const float*)d_in[15];
    const float* bj2    = (const float*)d_in[16];

    float* out = (float*)d_out;
    float* logits_out   = out;
    float* out_lens_out = out + (size_t)BB * TT * E_DIM;
    float* labels_out   = out_lens_out + BB;
    float* counts_out   = labels_out + (size_t)BB * LBUF;

    float* ws = (float*)d_ws;
    float* Fproj = ws + OFF_FPROJ;
    float* W0T   = ws + OFF_W0T;
    float* W1aT  = ws + OFF_W1AT;
    float* W1bT  = ws + OFF_W1BT;
    float* WjhT  = ws + OFF_WJHT;
    float* EP    = ws + OFF_EP;
    float* b1    = ws + OFF_B1;
    float* Wj2T  = ws + OFF_WJ2T;
    float* H0    = ws + OFF_H0;
    float* C0    = ws + OFF_C0;
    float* H1    = ws + OFF_H1;
    float* C1    = ws + OFF_C1;
    float* HP    = ws + OFF_HP;
    int*   flags = (int*)(ws + OFF_FLAGS);
    unsigned* bar = (unsigned*)(ws + OFF_BAR);

    {
        int total = 409600 + 163840 + G4 + VV * JHD;
        int blocks = (total + 255) / 256;
        prep_t_kernel<<<blocks, 256, 0, stream>>>(Whh0, Wih1, Whh1, Wj1, bih1, bhh1,
                                                  Wj2, W0T, W1aT, W1bT, WjhT, b1, Wj2T);
    }
    ep_kernel<<<VV, 256, 0, stream>>>(embed, Wih0, bih0, bhh0, EP);
    enc_fproj_kernel<<<(BB * TT) / 8, 512, 0, stream>>>(x, Wenc, benc, Wj1, bj1,
                                                        logits_out, Fproj);
    init_kernel<<<1, 1024, 0, stream>>>(lens, ws, out_lens_out, labels_out);
    decode_persistent<<<NB, 1024, 0, stream>>>(lens, Fproj, W0T, W1aT, W1bT, WjhT,
                                               Wj2T, EP, b1, bj2,
                                               H0, C0, H1, C1, HP, flags, bar,
                                               labels_out, counts_out);
}

// Round 3
// 23713.116 us; speedup vs baseline: 1.4222x; 1.4222x over previous
//
#include <hip/hip_runtime.h>
#include <math.h>

// Problem constants
#define BB 16
#define TT 128
#define F_IN 240
#define E_DIM 1024
#define HH 320
#define G4 1280        // 4*H
#define JHD 512
#define VV 29
#define BLANKV 28
#define MAXSYM 3
#define LBUF (TT*MAXSYM) // 384

#define NB 40          // persistent grid blocks (all co-resident on 256 CUs)
#define CBLK 32        // blocks participating in phase C (512 j / 16 each)
#define SBUF 5120      // per-state-buffer stride (16*320)
#define HPITCH 328     // padded LDS row pitch for h vectors (floats, 16B aligned)

// Workspace layout (float offsets)
#define OFF_FPROJ  0ul                         // 2048*512 = 1048576
#define OFF_WJHR   1048576ul                   // 512*320 row-major (j,k)
#define OFF_EP     (OFF_WJHR + 163840ul)       // 29*1280
#define OFF_B1     (OFF_EP + 37120ul)          // 1280
#define OFF_H0     (OFF_B1 + 1280ul)           // 2*16*320
#define OFF_H1     (OFF_H0 + 10240ul)          // 2*16*320
#define OFF_PLOG   (OFF_H1 + 10240ul)          // 32*464
#define OFF_ARRIVE (OFF_PLOG + 14848ul)        // 2048 ints (padded flags)

__device__ __forceinline__ float sigmoidf_(float x) {
    return 1.0f / (1.0f + expf(-x));
}
__device__ __forceinline__ float ld_agent(const float* p) {
    return __hip_atomic_load(p, __ATOMIC_RELAXED, __HIP_MEMORY_SCOPE_AGENT);
}
__device__ __forceinline__ void st_agent(float* p, float v) {
    __hip_atomic_store(p, v, __ATOMIC_RELAXED, __HIP_MEMORY_SCOPE_AGENT);
}

// ---- Prep: WjhR[j][k] = Wj1[1024+k][j]; b1 = bih1 + bhh1 ----
__global__ void prep_t_kernel(const float* __restrict__ Wj1,
                              const float* __restrict__ bih1,
                              const float* __restrict__ bhh1,
                              float* __restrict__ WjhR, float* __restrict__ b1) {
    int idx = blockIdx.x * 256 + threadIdx.x;
    if (idx < 163840) {
        int j = idx / 320, k = idx - j * 320;
        WjhR[idx] = Wj1[(size_t)(1024 + k) * JHD + j];
        return;
    }
    int i2 = idx - 163840;
    if (i2 < G4) b1[i2] = bih1[i2] + bhh1[i2];
}

// ---- Prep: EP[v][j] = embed[v] @ Wih0[j,:] + bih0[j] + bhh0[j]; row 28 = bias only
__global__ void ep_kernel(const float* __restrict__ embed,
                          const float* __restrict__ Wih0,
                          const float* __restrict__ bih0,
                          const float* __restrict__ bhh0,
                          float* __restrict__ EP) {
    __shared__ __align__(16) float es[HH];
    int v = blockIdx.x;
    for (int k = threadIdx.x; k < HH; k += 256)
        es[k] = (v < VV - 1) ? embed[v * HH + k] : 0.0f;
    __syncthreads();
    for (int j = threadIdx.x; j < G4; j += 256) {
        float acc = bih0[j] + bhh0[j];
        if (v < VV - 1) {
            const float4* wr = (const float4*)(Wih0 + (size_t)j * HH);
            const float4* ev = (const float4*)es;
            #pragma unroll 4
            for (int k4 = 0; k4 < HH / 4; ++k4) {
                float4 w = wr[k4], e = ev[k4];
                acc += w.x * e.x + w.y * e.y + w.z * e.z + w.w * e.w;
            }
        }
        EP[v * G4 + j] = acc;
    }
}

// ---- Encoder + F_proj fused ----
__global__ __launch_bounds__(512) void enc_fproj_kernel(
    const float* __restrict__ x, const float* __restrict__ Wenc,
    const float* __restrict__ benc, const float* __restrict__ Wj1,
    const float* __restrict__ bj1,
    float* __restrict__ logits_out, float* __restrict__ Fproj) {
    __shared__ float xs[8][F_IN];
    __shared__ float ls[8][E_DIM];
    int row0 = blockIdx.x * 8;
    int tid = threadIdx.x;
    for (int i = tid; i < 8 * F_IN; i += 512)
        xs[i / F_IN][i % F_IN] = x[(size_t)row0 * F_IN + i];
    __syncthreads();
    for (int j = tid; j < E_DIM; j += 512) {
        float acc[8];
        float bv = benc[j];
        #pragma unroll
        for (int r = 0; r < 8; ++r) acc[r] = bv;
        for (int k = 0; k < F_IN; ++k) {
            float w = Wenc[(size_t)k * E_DIM + j];
            #pragma unroll
            for (int r = 0; r < 8; ++r) acc[r] += xs[r][k] * w;
        }
        #pragma unroll
        for (int r = 0; r < 8; ++r) {
            ls[r][j] = acc[r];
            logits_out[(size_t)(row0 + r) * E_DIM + j] = acc[r];
        }
    }
    __syncthreads();
    {
        int j = tid;
        float acc[8];
        float bv = bj1[j];
        #pragma unroll
        for (int r = 0; r < 8; ++r) acc[r] = bv;
        for (int k = 0; k < E_DIM; ++k) {
            float w = Wj1[(size_t)k * JHD + j];
            #pragma unroll
            for (int r = 0; r < 8; ++r) acc[r] += ls[r][k] * w;
        }
        #pragma unroll
        for (int r = 0; r < 8; ++r) Fproj[(size_t)(row0 + r) * JHD + j] = acc[r];
    }
}

// ---- Init: zero state + arrive flags; labels=-1; out_lens passthrough ----
__global__ void init_kernel(const int* __restrict__ lens, float* ws,
                            float* __restrict__ out_lens_out,
                            float* __restrict__ labels_out) {
    int tid = threadIdx.x;
    float* h0 = ws + OFF_H0;
    for (int i = tid; i < 20480; i += 1024) h0[i] = 0.0f;   // H0 + H1, both buffers
    int* arr = (int*)(ws + OFF_ARRIVE);
    for (int i = tid; i < 2048; i += 1024) arr[i] = 0;
    for (int i = tid; i < BB * LBUF; i += 1024) labels_out[i] = -1.0f;
    if (tid < BB) out_lens_out[tid] = (float)lens[tid];
}

// ---- Distributed flag barrier: no atomics, no cache-maintenance fences ----
__device__ __forceinline__ void gbar(int* arrive, int e) {
    // every wave drains its outstanding (write-through) stores first
    asm volatile("s_waitcnt vmcnt(0)" ::: "memory");
    __syncthreads();
    if (threadIdx.x < 64) {
        int lane = threadIdx.x;
        if (lane == 0)
            __hip_atomic_store(&arrive[blockIdx.x * 32], e,
                               __ATOMIC_RELAXED, __HIP_MEMORY_SCOPE_AGENT);
        if (lane < NB) {
            while (__hip_atomic_load(&arrive[lane * 32],
                                     __ATOMIC_RELAXED, __HIP_MEMORY_SCOPE_AGENT) < e)
                __builtin_amdgcn_s_sleep(4);
        }
    }
    asm volatile("" ::: "memory");
    __syncthreads();
}

// ---- Persistent lockstep decoder: 40 blocks x 1024 threads, 3 barriers/slot ----
__global__ __launch_bounds__(1024) void decode_persistent(
    const int* __restrict__ lens,
    const float* __restrict__ Fproj,
    const float* __restrict__ W0,    // Whh0 [1280][320]
    const float* __restrict__ W1a,   // Wih1 [1280][320]
    const float* __restrict__ W1b,   // Whh1 [1280][320]
    const float* __restrict__ WjhR,  // [512][320]
    const float* __restrict__ Wj2,   // [512][29]
    const float* __restrict__ EP, const float* __restrict__ b1,
    const float* __restrict__ bj2,
    float* H0, float* H1, float* plog, int* arrive,
    float* __restrict__ labels_out, float* __restrict__ counts_out) {

    const int tid = threadIdx.x;
    const int blk = blockIdx.x;

    __shared__ __align__(16) float sh_a[16 * HPITCH];
    __shared__ __align__(16) float sh_b[16 * HPITCH];
    __shared__ float sh_g[32 * 17];
    __shared__ float sh_lg[16 * 30];
    __shared__ int curL[16], lastL[16], contL[16], cntL[16], lenL[16];
    __shared__ int sMaxL;

    if (tid < 16) {
        curL[tid] = 0; lastL[tid] = BLANKV; contL[tid] = 0; cntL[tid] = 0;
        lenL[tid] = lens[tid];
    }
    if (tid == 0) {
        int m = 0;
        for (int i = 0; i < BB; ++i) m = max(m, lens[i]);
        sMaxL = m;
    }
    __syncthreads();
    const int maxL = sMaxL;

    // lane decomposition for A/B: b_lo(2b) kc(4b) bh(2b) jg(2b)
    const int b_lo = tid & 3;
    const int kc   = (tid >> 2) & 15;
    const int bh   = (tid >> 6) & 3;
    const int jg   = tid >> 8;             // 0..3 = gate type (A/B) / j-group (C)
    const int b    = (bh << 2) | b_lo;
    const int kf   = kc * 20;              // float offset of this lane's k-chunk

    // cell states: thread-private for the 128 update threads (b=tid&15, u=tid>>4)
    const int ub = tid & 15, uu = tid >> 4;
    float c0A = 0.f, c0B = 0.f, c1A = 0.f, c1B = 0.f;

    int epoch = 0;

    for (int slot = 0; slot < 3 * maxL; ++slot) {
        const int t = slot / 3;
        const int s = slot - t * 3;

        // ========== Phase A: LSTM cell 0 ==========
        for (int idx = tid; idx < SBUF; idx += 1024) {
            int ib = idx / 320, k = idx - ib * 320;
            sh_a[ib * HPITCH + k] = ld_agent(H0 + curL[ib] * SBUF + idx);
        }
        __syncthreads();
        {
            const float4* hv = (const float4*)(sh_a + b * HPITCH + kf);
            const float*  w0 = W0 + (size_t)(jg * 320 + blk * 8) * 320 + kf;
            float acc[8] = {0.f,0.f,0.f,0.f,0.f,0.f,0.f,0.f};
            #pragma unroll
            for (int q = 0; q < 5; ++q) {
                float4 h = hv[q];
                #pragma unroll
                for (int jj = 0; jj < 8; ++jj) {
                    float4 w = *(const float4*)(w0 + jj * 320 + q * 4);
                    acc[jj] += h.x * w.x + h.y * w.y + h.z * w.z + h.w * w.w;
                }
            }
            #pragma unroll
            for (int jj = 0; jj < 8; ++jj) {
                float a = acc[jj];
                a += __shfl_xor(a, 4);  a += __shfl_xor(a, 8);
                a += __shfl_xor(a, 16); a += __shfl_xor(a, 32);
                acc[jj] = a;
            }
            if (kc == 0) {
                const float* ep = EP + (size_t)lastL[b] * G4 + jg * 320 + blk * 8;
                #pragma unroll
                for (int jj = 0; jj < 8; ++jj)
                    sh_g[(jg * 8 + jj) * 17 + b] = acc[jj] + ep[jj];
            }
        }
        __syncthreads();
        if (tid < 128) {
            int cb = curL[ub];
            int i  = blk * 8 + uu;
            float xi = sh_g[(0 * 8 + uu) * 17 + ub];
            float xf = sh_g[(1 * 8 + uu) * 17 + ub];
            float xg = sh_g[(2 * 8 + uu) * 17 + ub];
            float xo = sh_g[(3 * 8 + uu) * 17 + ub];
            float cold = cb ? c0B : c0A;
            float c = sigmoidf_(xf) * cold + sigmoidf_(xi) * tanhf(xg);
            if (cb) c0A = c; else c0B = c;      // write pend slot
            st_agent(H0 + (cb ^ 1) * SBUF + ub * 320 + i, sigmoidf_(xo) * tanhf(c));
        }
        gbar(arrive, ++epoch);

        // ========== Phase B: LSTM cell 1 ==========
        for (int idx = tid; idx < SBUF; idx += 1024) {
            int ib = idx / 320, k = idx - ib * 320;
            sh_a[ib * HPITCH + k] = ld_agent(H0 + (curL[ib] ^ 1) * SBUF + idx);
        }
        for (int idx = tid; idx < SBUF; idx += 1024) {
            int ib = idx / 320, k = idx - ib * 320;
            sh_b[ib * HPITCH + k] = ld_agent(H1 + curL[ib] * SBUF + idx);
        }
        __syncthreads();
        {
            const float4* ha = (const float4*)(sh_a + b * HPITCH + kf);
            const float4* hb = (const float4*)(sh_b + b * HPITCH + kf);
            const float*  wa = W1a + (size_t)(jg * 320 + blk * 8) * 320 + kf;
            const float*  wb = W1b + (size_t)(jg * 320 + blk * 8) * 320 + kf;
            float acc[8] = {0.f,0.f,0.f,0.f,0.f,0.f,0.f,0.f};
            #pragma unroll
            for (int q = 0; q < 5; ++q) {
                float4 x = ha[q], y = hb[q];
                #pragma unroll
                for (int jj = 0; jj < 8; ++jj) {
                    float4 w1 = *(const float4*)(wa + jj * 320 + q * 4);
                    float4 w2 = *(const float4*)(wb + jj * 320 + q * 4);
                    acc[jj] += x.x * w1.x + x.y * w1.y + x.z * w1.z + x.w * w1.w
                             + y.x * w2.x + y.y * w2.y + y.z * w2.z + y.w * w2.w;
                }
            }
            #pragma unroll
            for (int jj = 0; jj < 8; ++jj) {
                float a = acc[jj];
                a += __shfl_xor(a, 4);  a += __shfl_xor(a, 8);
                a += __shfl_xor(a, 16); a += __shfl_xor(a, 32);
                acc[jj] = a;
            }
            if (kc == 0) {
                const float* bb1 = b1 + jg * 320 + blk * 8;
                #pragma unroll
                for (int jj = 0; jj < 8; ++jj)
                    sh_g[(jg * 8 + jj) * 17 + b] = acc[jj] + bb1[jj];
            }
        }
        __syncthreads();
        if (tid < 128) {
            int cb = curL[ub];
            int i  = blk * 8 + uu;
            float xi = sh_g[(0 * 8 + uu) * 17 + ub];
            float xf = sh_g[(1 * 8 + uu) * 17 + ub];
            float xg = sh_g[(2 * 8 + uu) * 17 + ub];
            float xo = sh_g[(3 * 8 + uu) * 17 + ub];
            float cold = cb ? c1B : c1A;
            float c = sigmoidf_(xf) * cold + sigmoidf_(xi) * tanhf(xg);
            if (cb) c1A = c; else c1B = c;
            st_agent(H1 + (cb ^ 1) * SBUF + ub * 320 + i, sigmoidf_(xo) * tanhf(c));
        }
        gbar(arrive, ++epoch);

        // ========== Phase C: HP j-slice + partial logits (blocks 0..31) ==========
        if (blk < CBLK) {
            for (int idx = tid; idx < SBUF; idx += 1024) {
                int ib = idx / 320, k = idx - ib * 320;
                sh_a[ib * HPITCH + k] = ld_agent(H1 + (curL[ib] ^ 1) * SBUF + idx);
            }
            __syncthreads();
            {
                const float4* hv = (const float4*)(sh_a + b * HPITCH + kf);
                const float*  wc = WjhR + (size_t)(blk * 16 + jg * 4) * 320 + kf;
                float acc[4] = {0.f,0.f,0.f,0.f};
                #pragma unroll
                for (int q = 0; q < 5; ++q) {
                    float4 h = hv[q];
                    #pragma unroll
                    for (int jj = 0; jj < 4; ++jj) {
                        float4 w = *(const float4*)(wc + jj * 320 + q * 4);
                        acc[jj] += h.x * w.x + h.y * w.y + h.z * w.z + h.w * w.w;
                    }
                }
                #pragma unroll
                for (int jj = 0; jj < 4; ++jj) {
                    float a = acc[jj];
                    a += __shfl_xor(a, 4);  a += __shfl_xor(a, 8);
                    a += __shfl_xor(a, 16); a += __shfl_xor(a, 32);
                    acc[jj] = a;
                }
                if (kc == 0) {
                    const float* fp = Fproj + ((size_t)b * TT + t) * JHD + blk * 16 + jg * 4;
                    #pragma unroll
                    for (int jj = 0; jj < 4; ++jj)
                        sh_g[(jg * 4 + jj) * 17 + b] = fmaxf(fp[jj] + acc[jj], 0.f);
                }
            }
            __syncthreads();
            if (tid < 464) {
                int b2 = tid / 29, v = tid - b2 * 29;
                float p = 0.f;
                #pragma unroll
                for (int jl = 0; jl < 16; ++jl)
                    p += sh_g[jl * 17 + b2] * Wj2[(size_t)(blk * 16 + jl) * VV + v];
                st_agent(plog + blk * 464 + tid, p);
            }
        }
        gbar(arrive, ++epoch);

        // ========== Phase D: reduce partials + argmax + commit (replicated) ==========
        if (tid < 464) {
            int b2 = tid / 29, v = tid - b2 * 29;
            float acc = bj2[v];
            #pragma unroll
            for (int r = 0; r < 32; ++r)
                acc += ld_agent(plog + r * 464 + tid);
            sh_lg[b2 * 30 + v] = acc;
        }
        __syncthreads();
        if (tid < 16) {
            float best = sh_lg[tid * 30];
            int k = 0;
            #pragma unroll
            for (int v = 1; v < VV; ++v) {
                float x = sh_lg[tid * 30 + v];
                if (x > best) { best = x; k = v; }
            }
            bool active = (t < lenL[tid]) && (s == 0 || contL[tid]);
            bool emit = active && (k != BLANKV);
            if (emit) {
                if (blk == 0)
                    labels_out[(size_t)tid * LBUF + cntL[tid]] = (float)k;
                cntL[tid]++; lastL[tid] = k; curL[tid] ^= 1; contL[tid] = 1;
            } else {
                contL[tid] = 0;
            }
        }
        __syncthreads();
        // no barrier here: next slot's writes can't collide before barrier 1/2
    }

    if (blk == 0 && tid < 16) counts_out[tid] = (float)cntL[tid];
}

extern "C" void kernel_launch(void* const* d_in, const int* in_sizes, int n_in,
                              void* d_out, int out_size, void* d_ws, size_t ws_size,
                              hipStream_t stream) {
    const float* x      = (const float*)d_in[0];
    const int*   lens   = (const int*)d_in[1];
    const float* Wenc   = (const float*)d_in[2];
    const float* benc   = (const float*)d_in[3];
    const float* embed  = (const float*)d_in[4];
    const float* Wih0   = (const float*)d_in[5];
    const float* Whh0   = (const float*)d_in[6];
    const float* bih0   = (const float*)d_in[7];
    const float* bhh0   = (const float*)d_in[8];
    const float* Wih1   = (const float*)d_in[9];
    const float* Whh1   = (const float*)d_in[10];
    const float* bih1   = (const float*)d_in[11];
    const float* bhh1   = (const float*)d_in[12];
    const float* Wj1    = (const float*)d_in[13];
    const float* bj1    = (const float*)d_in[14];
    const float* Wj2    = (const float*)d_in[15];
    const float* bj2    = (const float*)d_in[16];

    float* out = (float*)d_out;
    float* logits_out   = out;
    float* out_lens_out = out + (size_t)BB * TT * E_DIM;
    float* labels_out   = out_lens_out + BB;
    float* counts_out   = labels_out + (size_t)BB * LBUF;

    float* ws    = (float*)d_ws;
    float* Fproj = ws + OFF_FPROJ;
    float* WjhR  = ws + OFF_WJHR;
    float* EP    = ws + OFF_EP;
    float* b1    = ws + OFF_B1;
    float* H0    = ws + OFF_H0;
    float* H1    = ws + OFF_H1;
    float* plog  = ws + OFF_PLOG;
    int*   arrive = (int*)(ws + OFF_ARRIVE);

    {
        int total = 163840 + G4;
        prep_t_kernel<<<(total + 255) / 256, 256, 0, stream>>>(Wj1, bih1, bhh1, WjhR, b1);
    }
    ep_kernel<<<VV, 256, 0, stream>>>(embed, Wih0, bih0, bhh0, EP);
    enc_fproj_kernel<<<(BB * TT) / 8, 512, 0, stream>>>(x, Wenc, benc, Wj1, bj1,
                                                        logits_out, Fproj);
    init_kernel<<<1, 1024, 0, stream>>>(lens, ws, out_lens_out, labels_out);
    decode_persistent<<<NB, 1024, 0, stream>>>(lens, Fproj, Whh0, Wih1, Whh1,
                                               WjhR, Wj2, EP, b1, bj2,
                                               H0, H1, plog, arrive,
                                               labels_out, counts_out);
}